// Round 6
// baseline (182.054 us; speedup 1.0000x reference)
//
#include <hip/hip_runtime.h>
#include <math.h>

#define M_SPATIAL 2097152  // 128^3
#define MV4 (M_SPATIAL / 4)

__device__ __forceinline__ float wave_redf(float v) {
#pragma unroll
  for (int o = 32; o > 0; o >>= 1) v += __shfl_down(v, o, 64);
  return v;
}
__device__ __forceinline__ double wave_redd(double v) {
#pragma unroll
  for (int o = 32; o > 0; o >>= 1) v += __shfl_down(v, o, 64);
  return v;
}

// part layout (doubles):
// [0..1023]=ce  [1024..2047]=p  [2048..3071]=pt  [3072..4095]=t  [4096..4351]=dist
// kA blocks 0..511 -> b=0, 512..1023 -> b=1.

// ---------------------------------------------------------------------------
// kA: streaming CE + dice partials (float4/int4, per-block slots, no atomics).
// ---------------------------------------------------------------------------
__global__ __launch_bounds__(256) void kA_ce(const float4* __restrict__ outputs4,
                                             const int4* __restrict__ y4,
                                             double* __restrict__ part) {
  int blk = blockIdx.x;                 // 0..1023
  int base = blk * 1024;                // vec4 slots
  int b = (blk >= 512) ? 1 : 0;
  const float4* xc = outputs4 + (size_t)(b * 2 + 1) * MV4;
  float ce = 0.f, ps = 0.f, pts = 0.f, tsum = 0.f;
#pragma unroll
  for (int k = 0; k < 4; ++k) {
    int v4 = base + (int)threadIdx.x + k * 256;
    int s4 = v4 & (MV4 - 1);
    int4 yv = y4[v4];
    float4 x = xc[s4];
#define ELEM(c, yc)                                                         \
    {                                                                       \
      float t = (yc == 1) ? 1.0f : 0.0f;                                    \
      float xx = x.c;                                                       \
      ce += fmaxf(xx, 0.0f) - xx * t + log1pf(expf(-fabsf(xx)));            \
      float p = 1.0f / (1.0f + expf(-xx));                                  \
      ps += p; pts += p * t; tsum += t;                                     \
    }
    ELEM(x, yv.x) ELEM(y, yv.y) ELEM(z, yv.z) ELEM(w, yv.w)
#undef ELEM
  }
  float r0 = wave_redf(ce), r1 = wave_redf(ps), r2 = wave_redf(pts), r3 = wave_redf(tsum);
  __shared__ float sm[4][4];
  int lane = threadIdx.x & 63, w = threadIdx.x >> 6;
  if (lane == 0) { sm[w][0] = r0; sm[w][1] = r1; sm[w][2] = r2; sm[w][3] = r3; }
  __syncthreads();
  if (threadIdx.x == 0) {
    part[blk]        = (double)(sm[0][0] + sm[1][0] + sm[2][0] + sm[3][0]);
    part[1024 + blk] = (double)(sm[0][1] + sm[1][1] + sm[2][1] + sm[3][1]);
    part[2048 + blk] = (double)(sm[0][2] + sm[1][2] + sm[2][2] + sm[3][2]);
    part[3072 + blk] = (double)(sm[0][3] + sm[1][3] + sm[2][3] + sm[3][3]);
  }
}

// ---------------------------------------------------------------------------
// kBX: X-axis EDT, brute-force 2-op envelope (high occupancy, no serial scan).
// Block = (b, yy, 32-z chunk). Stage S[j=x][z] = (y==1 ? 1e6 : 0) + j^2.
// Thread (zl, ig) computes i = ig*16..+15:  gX(i) = i^2 + min_j(S[j] - 2ij).
// Writes h = gX + yy^2 for the Y pass. All values exact ints < 2^21 in fp32.
// ---------------------------------------------------------------------------
__global__ __launch_bounds__(256) void kBX_edtx(const int* __restrict__ y,
                                                float* __restrict__ g) {
  __shared__ float S[128 * 32];    // 16 KB
  int blk = blockIdx.x;            // b*512 + yy*4 + zc
  int b = blk >> 9, yy = (blk >> 2) & 127, zc = blk & 3;
  int t = threadIdx.x;
  size_t tb = (size_t)b * M_SPATIAL + (size_t)yy * 128 + (size_t)zc * 32;

  // Stage: 128 rows (j=x, stride 16384) x 32 z (contiguous, int4).
#pragma unroll
  for (int r = 0; r < 4; ++r) {
    int i4 = t + r * 256;          // 0..1023
    int j = i4 >> 3, c = (i4 & 7) * 4;
    const int4 vv = *(const int4*)(y + tb + (size_t)j * 16384 + c);
    float j2 = (float)(j * j);
    S[j * 32 + c + 0] = ((vv.x == 1) ? 1000000.f : 0.f) + j2;
    S[j * 32 + c + 1] = ((vv.y == 1) ? 1000000.f : 0.f) + j2;
    S[j * 32 + c + 2] = ((vv.z == 1) ? 1000000.f : 0.f) + j2;
    S[j * 32 + c + 3] = ((vv.w == 1) ? 1000000.f : 0.f) + j2;
  }
  __syncthreads();

  int zl = t & 31, ig = t >> 5;    // ig 0..7
  float best[16], mc[16];
#pragma unroll
  for (int k = 0; k < 16; ++k) {
    best[k] = 3.0e38f;
    mc[k] = -2.0f * (float)(ig * 16 + k);
  }
#pragma unroll 4
  for (int j = 0; j < 128; ++j) {
    float hj = S[j * 32 + zl];     // 2-way broadcast, conflict-free
    float jf = (float)j;
#pragma unroll
    for (int k = 0; k < 16; ++k) best[k] = fminf(best[k], fmaf(mc[k], jf, hj));
  }
  float yq = (float)(yy * yy);
  size_t ob = tb + zl;
#pragma unroll
  for (int k = 0; k < 16; ++k) {
    int i = ig * 16 + k;
    g[ob + (size_t)i * 16384] = (float)(i * i) + best[k] + yq;  // h = gX + yy^2
  }
}

// ---------------------------------------------------------------------------
// kYZ: fused Y-pass + Z-pass + dist partial. Block = (b, x): the 128x128 (y,z)
// slab is 16384 contiguous floats -> one 64 KB LDS buffer, reused (in-place
// transposed repack) between passes. 1024 threads.
// ---------------------------------------------------------------------------
__global__ __launch_bounds__(1024) void kYZ_dist(const float* __restrict__ g,
                                                 const float* __restrict__ od,
                                                 double* __restrict__ part) {
  __shared__ float S[128 * 128];   // 64 KB, unpadded
  __shared__ float sred[16];
  int blk = blockIdx.x;            // b*128 + xx
  int b = blk >> 7, xx = blk & 127;
  int t = threadIdx.x;
  size_t rb = (size_t)b * M_SPATIAL + (size_t)xx * 16384;

  // Stage-in: S[y*128+z] = h(y,z), fully coalesced float4.
  const float4* g4 = (const float4*)(g + rb);
#pragma unroll
  for (int r = 0; r < 4; ++r) {
    int i4 = t + r * 1024;
    *(float4*)(S + i4 * 4) = g4[i4];
  }
  __syncthreads();

  int zl = t & 127, ig = t >> 7;   // ig 0..7; i = ig*16+k
  float best[16], mc[16];
#pragma unroll
  for (int k = 0; k < 16; ++k) {
    best[k] = 3.0e38f;
    mc[k] = -2.0f * (float)(ig * 16 + k);
  }
  // --- Y pass: lines along y for fixed z=zl; reads S[j*128+zl] (conflict-free)
#pragma unroll 4
  for (int j = 0; j < 128; ++j) {
    float hj = S[j * 128 + zl];
    float jf = (float)j;
#pragma unroll
    for (int k = 0; k < 16; ++k) best[k] = fminf(best[k], fmaf(mc[k], jf, hj));
  }
  // B(z, y=i) = dY + z^2 = i^2 + best + z^2  (exact int < 2^21)
  float zq = (float)(zl * zl);
  float outv[16];
#pragma unroll
  for (int k = 0; k < 16; ++k) {
    int i = ig * 16 + k;
    outv[k] = (float)(i * i) + best[k] + zq;
  }
  __syncthreads();                 // all Y-pass reads of S complete
  // Repack transposed in-place: S[z*128 + y]. 32-way conflict on 16 stores
  // (~4% of block time) — cheaper than padding (would exceed 64 KB).
#pragma unroll
  for (int k = 0; k < 16; ++k) S[zl * 128 + ig * 16 + k] = outv[k];
  __syncthreads();

  // Prefetch od for the dist epilogue: thread owns (y=zl, z = ig*16..+15) -> 64 B.
  size_t odb = (size_t)(2 * b + 1) * M_SPATIAL + (size_t)xx * 16384 +
               (size_t)zl * 128 + (size_t)ig * 16;
  const float4* o4 = (const float4*)(od + odb);
  float4 ov[4];
#pragma unroll
  for (int r = 0; r < 4; ++r) ov[r] = o4[r];

  // --- Z pass: lines along z for fixed y=zl; reads S[j*128+zl] (conflict-free)
#pragma unroll
  for (int k = 0; k < 16; ++k) best[k] = 3.0e38f;
#pragma unroll 4
  for (int j = 0; j < 128; ++j) {
    float hj = S[j * 128 + zl];
    float jf = (float)j;
#pragma unroll
    for (int k = 0; k < 16; ++k) best[k] = fminf(best[k], fmaf(mc[k], jf, hj));
  }
  const float* of = (const float*)ov;
  float dist = 0.f;
#pragma unroll
  for (int k = 0; k < 16; ++k) {
    int i = ig * 16 + k;
    float dv = (float)(i * i) + best[k];   // exact squared EDT
    if (dv > 0.f) dist += fabsf(of[k] - sqrtf(dv));
  }
  float r = wave_redf(dist);
  int lane = t & 63, w = t >> 6;
  if (lane == 0) sred[w] = r;
  __syncthreads();
  if (t == 0) {
    float s = 0.f;
#pragma unroll
    for (int w2 = 0; w2 < 16; ++w2) s += sred[w2];
    part[4096 + blk] = (double)s;
  }
}

// ---------------------------------------------------------------------------
// k_final: reduce partials (ce/p/pt/t: 1024 each; dist: 256), combine.
// ---------------------------------------------------------------------------
__global__ __launch_bounds__(256) void k_final(const double* __restrict__ part,
                                               const float* __restrict__ wptr,
                                               float* __restrict__ out) {
  int i = threadIdx.x;
  double ce  = part[i] + part[i + 256] + part[i + 512] + part[i + 768];
  double p0  = part[1024 + i] + part[1024 + i + 256];
  double p1  = part[1536 + i] + part[1536 + i + 256];
  double pt0 = part[2048 + i] + part[2048 + i + 256];
  double pt1 = part[2560 + i] + part[2560 + i + 256];
  double t0  = part[3072 + i] + part[3072 + i + 256];
  double t1  = part[3584 + i] + part[3584 + i + 256];
  double ds  = part[4096 + i];

  ce = wave_redd(ce); p0 = wave_redd(p0); p1 = wave_redd(p1);
  pt0 = wave_redd(pt0); pt1 = wave_redd(pt1);
  t0 = wave_redd(t0); t1 = wave_redd(t1); ds = wave_redd(ds);

  __shared__ double sm[4][8];
  int lane = threadIdx.x & 63, w = threadIdx.x >> 6;
  if (lane == 0) {
    sm[w][0] = ce; sm[w][1] = p0; sm[w][2] = p1; sm[w][3] = pt0;
    sm[w][4] = pt1; sm[w][5] = t0; sm[w][6] = t1; sm[w][7] = ds;
  }
  __syncthreads();
  if (threadIdx.x == 0) {
    double a[8];
    for (int q = 0; q < 8; ++q) a[q] = sm[0][q] + sm[1][q] + sm[2][q] + sm[3][q];
    double cem = a[0] / 4194304.0;
    double dice0 = (2.0 * a[3] + 1.0) / (a[1] + a[5] + 1.0);
    double dice1 = (2.0 * a[4] + 1.0) / (a[2] + a[6] + 1.0);
    double ldice = 1.0 - 0.5 * (dice0 + dice1);
    double msum = a[5] + a[6];
    double ldist = (msum == 0.0) ? 0.0 : a[7] / fmax(msum, 1e-12);
    out[0] = (float)(cem + ldice + (double)wptr[0] * ldist);
  }
}

extern "C" void kernel_launch(void* const* d_in, const int* in_sizes, int n_in,
                              void* d_out, int out_size, void* d_ws, size_t ws_size,
                              hipStream_t stream) {
  const float* outputs      = (const float*)d_in[0];
  const float* outputs_dist = (const float*)d_in[1];
  const int*   y            = (const int*)d_in[2];
  const float* wptr         = (const float*)d_in[3];
  float* out = (float*)d_out;

  double* part = (double*)d_ws;                    // 4352 doubles = 34 KiB
  float* g = (float*)((char*)d_ws + 65536);        // 16 MiB h field

  kA_ce<<<1024, 256, 0, stream>>>((const float4*)outputs, (const int4*)y, part);
  kBX_edtx<<<1024, 256, 0, stream>>>(y, g);        // X pass -> h = gX + y^2
  kYZ_dist<<<256, 1024, 0, stream>>>(g, outputs_dist, part);  // Y+Z+dist
  k_final<<<1, 256, 0, stream>>>(part, wptr, out);
}

// Round 7
// 180.907 us; speedup vs baseline: 1.0063x; 1.0063x over previous
//
#include <hip/hip_runtime.h>
#include <math.h>

#define M_SPATIAL 2097152  // 128^3

__device__ __forceinline__ float wave_redf(float v) {
#pragma unroll
  for (int o = 32; o > 0; o >>= 1) v += __shfl_down(v, o, 64);
  return v;
}
__device__ __forceinline__ double wave_redd(double v) {
#pragma unroll
  for (int o = 32; o > 0; o >>= 1) v += __shfl_down(v, o, 64);
  return v;
}

// part layout (doubles):
// [0..1023]=ce  [1024..2047]=p  [2048..3071]=pt  [3072..4095]=t  [4096..4351]=dist
// kAB blocks: blk = b*512 + yy*4 + zc  ->  0..511 b=0, 512..1023 b=1.

// ---------------------------------------------------------------------------
// kAB: fused CE/dice partials + X-axis EDT (brute-force 1.5-op envelope).
// Block = (b, yy, 32-z chunk). Stage S[j=x][z] = (y==1 ? 1e6 : 0) + j^2 while
// computing CE/dice from the ch-1 logits at the same addresses.
// Thread (zl, ig) computes i = ig*16..+15: writes h = i^2 + env + yy^2.
// All envelope values are exact integers < 2^21 in fp32 == reference bitwise.
// ---------------------------------------------------------------------------
__global__ __launch_bounds__(256) void kAB_ce_edtx(const float* __restrict__ outputs,
                                                   const int* __restrict__ y,
                                                   float* __restrict__ g,
                                                   double* __restrict__ part) {
  __shared__ float S[128 * 32];    // 16 KB
  __shared__ float sm[4][4];
  int blk = blockIdx.x;            // b*512 + yy*4 + zc
  int b = blk >> 9, yy = (blk >> 2) & 127, zc = blk & 3;
  int t = threadIdx.x;
  size_t sp = (size_t)yy * 128 + (size_t)zc * 32;      // spatial offset (no b)
  size_t tb = (size_t)b * M_SPATIAL + sp;              // y/g index
  const float* xc = outputs + (size_t)(2 * b + 1) * M_SPATIAL;  // ch-1 logits

  float ce = 0.f, ps = 0.f, pts = 0.f, tsum = 0.f;
#pragma unroll
  for (int r = 0; r < 4; ++r) {
    int i4 = t + r * 256;          // 0..1023
    int j = i4 >> 3, c = (i4 & 7) * 4;
    size_t off = (size_t)j * 16384 + c;
    const int4 vv = *(const int4*)(y + tb + off);
    const float4 xv = *(const float4*)(xc + sp + off);
    float j2 = (float)(j * j);
#define ELEM(idx, yc, xcomp)                                                \
    {                                                                       \
      float tt = (yc == 1) ? 1.0f : 0.0f;                                   \
      S[j * 32 + c + idx] = tt * 1000000.f + j2;                            \
      float xx = xcomp;                                                     \
      ce += fmaxf(xx, 0.0f) - xx * tt + log1pf(expf(-fabsf(xx)));           \
      float p = 1.0f / (1.0f + expf(-xx));                                  \
      ps += p; pts += p * tt; tsum += tt;                                   \
    }
    ELEM(0, vv.x, xv.x) ELEM(1, vv.y, xv.y) ELEM(2, vv.z, xv.z) ELEM(3, vv.w, xv.w)
#undef ELEM
  }
  __syncthreads();

  int zl = t & 31, ig = t >> 5;    // ig 0..7
  float best[16], mc[16];
#pragma unroll
  for (int k = 0; k < 16; ++k) {
    best[k] = 3.0e38f;
    mc[k] = -2.0f * (float)(ig * 16 + k);
  }
#pragma unroll 4
  for (int j = 0; j < 128; j += 2) {
    float h0 = S[j * 32 + zl];
    float h1 = S[(j + 1) * 32 + zl];
    float jf0 = (float)j, jf1 = (float)(j + 1);
#pragma unroll
    for (int k = 0; k < 16; ++k) {
      float e0 = fmaf(mc[k], jf0, h0);
      float e1 = fmaf(mc[k], jf1, h1);
      best[k] = fminf(best[k], fminf(e0, e1));   // -> v_min3_f32
    }
  }
  float yq = (float)(yy * yy);
  size_t ob = tb + zl;
#pragma unroll
  for (int k = 0; k < 16; ++k) {
    int i = ig * 16 + k;
    g[ob + (size_t)i * 16384] = (float)(i * i) + best[k] + yq;  // h = gX + yy^2
  }

  float r0 = wave_redf(ce), r1 = wave_redf(ps), r2 = wave_redf(pts), r3 = wave_redf(tsum);
  int lane = t & 63, w = t >> 6;
  if (lane == 0) { sm[w][0] = r0; sm[w][1] = r1; sm[w][2] = r2; sm[w][3] = r3; }
  __syncthreads();
  if (t == 0) {
    part[blk]        = (double)(sm[0][0] + sm[1][0] + sm[2][0] + sm[3][0]);
    part[1024 + blk] = (double)(sm[0][1] + sm[1][1] + sm[2][1] + sm[3][1]);
    part[2048 + blk] = (double)(sm[0][2] + sm[1][2] + sm[2][2] + sm[3][2]);
    part[3072 + blk] = (double)(sm[0][3] + sm[1][3] + sm[2][3] + sm[3][3]);
  }
}

// ---------------------------------------------------------------------------
// kYZ: fused Y-pass + Z-pass + dist partial, 1.5-op envelope.
// Block = (b, x): 128x128 (y,z) slab = 64 KB LDS, in-place transposed repack.
// ---------------------------------------------------------------------------
__global__ __launch_bounds__(1024) void kYZ_dist(const float* __restrict__ g,
                                                 const float* __restrict__ od,
                                                 double* __restrict__ part) {
  __shared__ float S[128 * 128];   // 64 KB, unpadded
  __shared__ float sred[16];
  int blk = blockIdx.x;            // b*128 + xx
  int b = blk >> 7, xx = blk & 127;
  int t = threadIdx.x;
  size_t rb = (size_t)b * M_SPATIAL + (size_t)xx * 16384;
  int zl = t & 127, ig = t >> 7;   // ig 0..7

  // Prefetch od early (independent of S): thread owns (y=zl, z=ig*16..+15).
  size_t odb = (size_t)(2 * b + 1) * M_SPATIAL + (size_t)xx * 16384 +
               (size_t)zl * 128 + (size_t)ig * 16;
  const float4* o4 = (const float4*)(od + odb);
  float4 ov[4];
#pragma unroll
  for (int r = 0; r < 4; ++r) ov[r] = o4[r];

  // Stage-in: S[y*128+z] = h(y,z), fully coalesced float4.
  const float4* g4 = (const float4*)(g + rb);
#pragma unroll
  for (int r = 0; r < 4; ++r) {
    int i4 = t + r * 1024;
    *(float4*)(S + i4 * 4) = g4[i4];
  }
  __syncthreads();

  float best[16], mc[16];
#pragma unroll
  for (int k = 0; k < 16; ++k) {
    best[k] = 3.0e38f;
    mc[k] = -2.0f * (float)(ig * 16 + k);
  }
  // --- Y pass: fixed z=zl; reads S[j*128+zl] (2-way = free)
#pragma unroll 4
  for (int j = 0; j < 128; j += 2) {
    float h0 = S[j * 128 + zl];
    float h1 = S[(j + 1) * 128 + zl];
    float jf0 = (float)j, jf1 = (float)(j + 1);
#pragma unroll
    for (int k = 0; k < 16; ++k) {
      float e0 = fmaf(mc[k], jf0, h0);
      float e1 = fmaf(mc[k], jf1, h1);
      best[k] = fminf(best[k], fminf(e0, e1));
    }
  }
  // B(z, y=i) = i^2 + best + z^2  (exact int < 2^21)
  float zq = (float)(zl * zl);
  float outv[16];
#pragma unroll
  for (int k = 0; k < 16; ++k) {
    int i = ig * 16 + k;
    outv[k] = (float)(i * i) + best[k] + zq;
  }
  __syncthreads();                 // all Y-pass reads of S complete
  // Repack transposed in-place: S[z*128 + y] (32-way on 16 stores, ~4%).
#pragma unroll
  for (int k = 0; k < 16; ++k) S[zl * 128 + ig * 16 + k] = outv[k];
  __syncthreads();

  // --- Z pass: fixed y=zl; reads S[j*128+zl]
#pragma unroll
  for (int k = 0; k < 16; ++k) best[k] = 3.0e38f;
#pragma unroll 4
  for (int j = 0; j < 128; j += 2) {
    float h0 = S[j * 128 + zl];
    float h1 = S[(j + 1) * 128 + zl];
    float jf0 = (float)j, jf1 = (float)(j + 1);
#pragma unroll
    for (int k = 0; k < 16; ++k) {
      float e0 = fmaf(mc[k], jf0, h0);
      float e1 = fmaf(mc[k], jf1, h1);
      best[k] = fminf(best[k], fminf(e0, e1));
    }
  }
  const float* of = (const float*)ov;
  float dist = 0.f;
#pragma unroll
  for (int k = 0; k < 16; ++k) {
    int i = ig * 16 + k;
    float dv = (float)(i * i) + best[k];   // exact squared EDT
    if (dv > 0.f) dist += fabsf(of[k] - sqrtf(dv));
  }
  float r = wave_redf(dist);
  int lane = t & 63, w = t >> 6;
  if (lane == 0) sred[w] = r;
  __syncthreads();
  if (t == 0) {
    float s = 0.f;
#pragma unroll
    for (int w2 = 0; w2 < 16; ++w2) s += sred[w2];
    part[4096 + blk] = (double)s;
  }
}

// ---------------------------------------------------------------------------
// k_final: reduce partials (ce/p/pt/t: 1024 each; dist: 256), combine.
// ---------------------------------------------------------------------------
__global__ __launch_bounds__(256) void k_final(const double* __restrict__ part,
                                               const float* __restrict__ wptr,
                                               float* __restrict__ out) {
  int i = threadIdx.x;
  double ce  = part[i] + part[i + 256] + part[i + 512] + part[i + 768];
  double p0  = part[1024 + i] + part[1024 + i + 256];
  double p1  = part[1536 + i] + part[1536 + i + 256];
  double pt0 = part[2048 + i] + part[2048 + i + 256];
  double pt1 = part[2560 + i] + part[2560 + i + 256];
  double t0  = part[3072 + i] + part[3072 + i + 256];
  double t1  = part[3584 + i] + part[3584 + i + 256];
  double ds  = part[4096 + i];

  ce = wave_redd(ce); p0 = wave_redd(p0); p1 = wave_redd(p1);
  pt0 = wave_redd(pt0); pt1 = wave_redd(pt1);
  t0 = wave_redd(t0); t1 = wave_redd(t1); ds = wave_redd(ds);

  __shared__ double sm[4][8];
  int lane = threadIdx.x & 63, w = threadIdx.x >> 6;
  if (lane == 0) {
    sm[w][0] = ce; sm[w][1] = p0; sm[w][2] = p1; sm[w][3] = pt0;
    sm[w][4] = pt1; sm[w][5] = t0; sm[w][6] = t1; sm[w][7] = ds;
  }
  __syncthreads();
  if (threadIdx.x == 0) {
    double a[8];
    for (int q = 0; q < 8; ++q) a[q] = sm[0][q] + sm[1][q] + sm[2][q] + sm[3][q];
    double cem = a[0] / 4194304.0;
    double dice0 = (2.0 * a[3] + 1.0) / (a[1] + a[5] + 1.0);
    double dice1 = (2.0 * a[4] + 1.0) / (a[2] + a[6] + 1.0);
    double ldice = 1.0 - 0.5 * (dice0 + dice1);
    double msum = a[5] + a[6];
    double ldist = (msum == 0.0) ? 0.0 : a[7] / fmax(msum, 1e-12);
    out[0] = (float)(cem + ldice + (double)wptr[0] * ldist);
  }
}

extern "C" void kernel_launch(void* const* d_in, const int* in_sizes, int n_in,
                              void* d_out, int out_size, void* d_ws, size_t ws_size,
                              hipStream_t stream) {
  const float* outputs      = (const float*)d_in[0];
  const float* outputs_dist = (const float*)d_in[1];
  const int*   y            = (const int*)d_in[2];
  const float* wptr         = (const float*)d_in[3];
  float* out = (float*)d_out;

  double* part = (double*)d_ws;                    // 4352 doubles = 34 KiB
  float* g = (float*)((char*)d_ws + 65536);        // 16 MiB h field

  kAB_ce_edtx<<<1024, 256, 0, stream>>>(outputs, y, g, part);  // CE + X pass
  kYZ_dist<<<256, 1024, 0, stream>>>(g, outputs_dist, part);   // Y+Z+dist
  k_final<<<1, 256, 0, stream>>>(part, wptr, out);
}